// Round 10
// baseline (924.492 us; speedup 1.0000x reference)
//
#include <hip/hip_runtime.h>
#include <stdint.h>

#define N_NODES 50000
#define N_EDGES 800000
#define B_GRAPHS 64
#define D_DIM 64
#define HD 128
#define G_GAUSS 50
#define HID_DIM 128
#define L_LAYERS 3
#define LN2 0.69314718055994530942f
#define PI_OVER_8 0.39269908169872414f
#define NCHUNK 196            // ceil(50000/256)

#define TN 64                 // nodes per node-GEMM block
#define TLD 132               // fp32 LDS leading dim for 128-wide tiles
#define XLD 68                // fp32 LDS leading dim for 64-wide tiles
#define NBLK ((N_NODES + TN - 1) / TN)   // 782

typedef __attribute__((ext_vector_type(8))) short bf16x8;
typedef __attribute__((ext_vector_type(4))) float f32x4;

__device__ __forceinline__ float sspf(float x) {
    float ax = fabsf(x);
    return fmaxf(x, 0.f) + __logf(1.f + __expf(-ax)) - LN2;
}
// non-stable variant: valid for |x| < ~80 (hid pre-activations are |x|<~5)
__device__ __forceinline__ float sspf_fast(float x) {
    return __logf(1.f + __expf(x)) - LN2;
}
__device__ __forceinline__ unsigned short f2bf(float f) {
    union { float f; unsigned int i; } v; v.f = f;
    unsigned int u = v.i;
    return (unsigned short)((u + 0x7FFFu + ((u >> 16) & 1u)) >> 16);
}

// ------------- one-time: bf16 transposed weights + zero counters/out -------------
#define PREP_W (L_LAYERS * 24576)     // 73728
__global__ void repr_prep(const float* __restrict__ fw1, const float* __restrict__ fw2,
                          short* __restrict__ w1t, short* __restrict__ w2t,
                          int* __restrict__ count_f, int* __restrict__ count_s,
                          float* __restrict__ dout) {
    int i = blockIdx.x * 256 + threadIdx.x;
    if (i < PREP_W) {
        int l = i / 24576, rem = i % 24576;
        if (rem < 8192) {
            int n = rem >> 6, k = rem & 63;
            float v = (k < G_GAUSS) ? fw1[(size_t)l * G_GAUSS * HID_DIM + k * HID_DIM + n] : 0.f;
            w1t[(size_t)l * 8192 + rem] = (short)f2bf(v);
        } else {
            int r2 = rem - 8192;
            int n = r2 >> 7, k = r2 & 127;
            float v = fw2[(size_t)l * HID_DIM * HD + k * HD + n];
            w2t[(size_t)l * 16384 + r2] = (short)f2bf(v);
        }
    } else {
        int j = i - PREP_W;
        if (j < N_NODES) count_f[j] = 0;
        else if (j < 2 * N_NODES) count_s[j - N_NODES] = 0;
        else if (j < 2 * N_NODES + B_GRAPHS) dout[j - 2 * N_NODES] = 0.f;
    }
}

// ------------- histograms (+ store r per edge) -------------
__global__ void repr_hist(const float* __restrict__ R,
                          const int* __restrict__ src, const int* __restrict__ dst,
                          int* __restrict__ count_f, int* __restrict__ count_s,
                          float* __restrict__ r_full) {
    int e = blockIdx.x * blockDim.x + threadIdx.x;
    if (e >= N_EDGES) return;
    int s = src[e], d = dst[e];
    atomicAdd(&count_f[d], 1);
    float dx = R[3*s+0] - R[3*d+0];
    float dy = R[3*s+1] - R[3*d+1];
    float dz = R[3*s+2] - R[3*d+2];
    float r = sqrtf(dx*dx + dy*dy + dz*dz);
    r_full[e] = r;
    if (r < 8.0f) atomicAdd(&count_s[d], 1);
}

// ------------- dual 2-level exclusive scan over 50000 counts -------------
__global__ void repr_scanA2(const int* __restrict__ cntA, int* __restrict__ exclA,
                            int* __restrict__ bsumA,
                            const int* __restrict__ cntB, int* __restrict__ exclB,
                            int* __restrict__ bsumB) {
    __shared__ int tmp[256];
    int t = threadIdx.x, b = blockIdx.x;
    const int* cnt; int* excl; int* bsum; int bb;
    if (b < NCHUNK) { cnt = cntA; excl = exclA; bsum = bsumA; bb = b; }
    else            { cnt = cntB; excl = exclB; bsum = bsumB; bb = b - NCHUNK; }
    int i = bb * 256 + t;
    int v = (i < N_NODES) ? cnt[i] : 0;
    tmp[t] = v; __syncthreads();
    for (int off = 1; off < 256; off <<= 1) {
        int add = (t >= off) ? tmp[t - off] : 0;
        __syncthreads();
        tmp[t] += add;
        __syncthreads();
    }
    if (i < N_NODES) excl[i] = tmp[t] - v;
    if (t == 255) bsum[bb] = tmp[255];
}
__global__ void repr_scanB2(const int* __restrict__ bsumA, int* __restrict__ bprefA,
                            int* __restrict__ ecA,
                            const int* __restrict__ bsumB, int* __restrict__ bprefB,
                            int* __restrict__ ecB) {
    __shared__ int tmp[256];
    const int* bsum = blockIdx.x ? bsumB : bsumA;
    int* bpref = blockIdx.x ? bprefB : bprefA;
    int* ec = blockIdx.x ? ecB : ecA;
    int t = threadIdx.x;
    int v = (t < NCHUNK) ? bsum[t] : 0;
    tmp[t] = v; __syncthreads();
    for (int off = 1; off < 256; off <<= 1) {
        int add = (t >= off) ? tmp[t - off] : 0;
        __syncthreads();
        tmp[t] += add;
        __syncthreads();
    }
    if (t < NCHUNK) bpref[t] = tmp[t] - v;
    if (t == 255) ec[0] = tmp[255];
}
__global__ void repr_scanC2(const int* __restrict__ exclA, const int* __restrict__ bprefA,
                            int* __restrict__ curA, int* __restrict__ rowptr,
                            const int* __restrict__ exclB, const int* __restrict__ bprefB,
                            int* __restrict__ curB) {
    int b = blockIdx.x;
    if (b < NCHUNK) {
        int i = b * 256 + threadIdx.x;
        if (i < N_NODES) { int v = exclA[i] + bprefA[b]; curA[i] = v; rowptr[i] = v; }
    } else {
        int i = (b - NCHUNK) * 256 + threadIdx.x;
        if (i < N_NODES) curB[i] = exclB[i] + bprefB[b - NCHUNK];
    }
}

// ------------- scatter: full dst-sorted list + survivor dst-sorted list -------------
__global__ void repr_scatter(const float* __restrict__ r_full,
                             const int* __restrict__ src, const int* __restrict__ dst,
                             int* __restrict__ cur_f, int* __restrict__ cur_s,
                             int* __restrict__ ssrc_f, int* __restrict__ sdst_f,
                             int* __restrict__ ssrc2, int* __restrict__ sdst2,
                             float* __restrict__ r2) {
    int e = blockIdx.x * blockDim.x + threadIdx.x;
    if (e >= N_EDGES) return;
    int s = src[e], d = dst[e];
    float r = r_full[e];
    int pos = atomicAdd(&cur_f[d], 1);
    ssrc_f[pos] = s; sdst_f[pos] = d;
    if (r < 8.0f) {
        int p2 = atomicAdd(&cur_s[d], 1);
        ssrc2[p2] = s; sdst2[p2] = d; r2[p2] = r;
    }
}

// ================= tiled fp32 node GEMMs (64 nodes / block, 256 threads) =================

__device__ __forceinline__ void load_ssp_agg(int base, int tid,
        const float* __restrict__ agg, float* __restrict__ bufA) {
    int row = tid >> 2;
    int c0 = (tid & 3) << 5;
    const float* ap = agg + (size_t)(base + row) * HD + c0;
    float* tp = bufA + row * TLD + c0;
    #pragma unroll
    for (int j = 0; j < 8; j++) {
        float4 v = *(const float4*)(ap + j * 4);
        tp[j*4+0] = sspf(v.x); tp[j*4+1] = sspf(v.y);
        tp[j*4+2] = sspf(v.z); tp[j*4+3] = sspf(v.w);
    }
}

__device__ __forceinline__ void gemm_mlp(int base, int tid,
        const float* __restrict__ w1, const float* __restrict__ b1,
        const float* __restrict__ w2, const float* __restrict__ b2,
        float* __restrict__ x, float* __restrict__ bufA, float* __restrict__ v1s)
{
    const int rg = tid >> 4, cg = tid & 15;
    const int r0 = rg * 4, c0 = cg * 4;
    float acc[4][4];
    #pragma unroll
    for (int r = 0; r < 4; r++)
        #pragma unroll
        for (int c = 0; c < 4; c++) acc[r][c] = 0.f;
    for (int k0 = 0; k0 < 128; k0 += 4) {
        float av[4][4];
        #pragma unroll
        for (int r = 0; r < 4; r++)
            *(float4*)av[r] = *(const float4*)&bufA[(r0 + r) * TLD + k0];
        #pragma unroll
        for (int kk = 0; kk < 4; kk++) {
            float4 wv = *(const float4*)(w1 + (k0 + kk) * 64 + c0);
            float wf[4] = {wv.x, wv.y, wv.z, wv.w};
            #pragma unroll
            for (int r = 0; r < 4; r++)
                #pragma unroll
                for (int c = 0; c < 4; c++)
                    acc[r][c] = fmaf(av[r][kk], wf[c], acc[r][c]);
        }
    }
    {
        float4 bv = *(const float4*)(b1 + c0);
        float ba[4] = {bv.x, bv.y, bv.z, bv.w};
        #pragma unroll
        for (int r = 0; r < 4; r++)
            #pragma unroll
            for (int c = 0; c < 4; c++)
                v1s[(r0 + r) * XLD + c0 + c] = sspf(acc[r][c] + ba[c]);
    }
    __syncthreads();
    float acc2[4][4];
    #pragma unroll
    for (int r = 0; r < 4; r++)
        #pragma unroll
        for (int c = 0; c < 4; c++) acc2[r][c] = 0.f;
    for (int k0 = 0; k0 < 64; k0 += 4) {
        float av[4][4];
        #pragma unroll
        for (int r = 0; r < 4; r++)
            *(float4*)av[r] = *(const float4*)&v1s[(r0 + r) * XLD + k0];
        #pragma unroll
        for (int kk = 0; kk < 4; kk++) {
            float4 wv = *(const float4*)(w2 + (k0 + kk) * 64 + c0);
            float wf[4] = {wv.x, wv.y, wv.z, wv.w};
            #pragma unroll
            for (int r = 0; r < 4; r++)
                #pragma unroll
                for (int c = 0; c < 4; c++)
                    acc2[r][c] = fmaf(av[r][kk], wf[c], acc2[r][c]);
        }
    }
    {
        float4 bv = *(const float4*)(b2 + c0);
        #pragma unroll
        for (int r = 0; r < 4; r++) {
            int n = base + r0 + r;
            float4 xv = *(const float4*)(x + (size_t)n * 64 + c0);
            float4 o;
            o.x = acc2[r][0] + bv.x + xv.x;
            o.y = acc2[r][1] + bv.y + xv.y;
            o.z = acc2[r][2] + bv.z + xv.z;
            o.w = acc2[r][3] + bv.w + xv.w;
            *(float4*)&bufA[(r0 + r) * XLD + c0] = o;
            if (n < N_NODES) *(float4*)(x + (size_t)n * 64 + c0) = o;
        }
    }
    __syncthreads();
}

__device__ __forceinline__ void gemm_h(int base, int tid,
        const float* __restrict__ bufA,
        const float* __restrict__ fc_w, const float* __restrict__ attn_l,
        const float* __restrict__ attn_r,
        float* __restrict__ h, float* __restrict__ el, float* __restrict__ er)
{
    const int rg = tid >> 4, cg = tid & 15;
    const int r0 = rg * 4, c0 = cg * 8;
    float acc[4][8];
    #pragma unroll
    for (int r = 0; r < 4; r++)
        #pragma unroll
        for (int c = 0; c < 8; c++) acc[r][c] = 0.f;
    for (int k0 = 0; k0 < 64; k0 += 4) {
        float av[4][4];
        #pragma unroll
        for (int r = 0; r < 4; r++)
            *(float4*)av[r] = *(const float4*)&bufA[(r0 + r) * XLD + k0];
        #pragma unroll
        for (int kk = 0; kk < 4; kk++) {
            float4 w0 = *(const float4*)(fc_w + (k0 + kk) * 128 + c0);
            float4 w1v = *(const float4*)(fc_w + (k0 + kk) * 128 + c0 + 4);
            float wf[8] = {w0.x, w0.y, w0.z, w0.w, w1v.x, w1v.y, w1v.z, w1v.w};
            #pragma unroll
            for (int r = 0; r < 4; r++)
                #pragma unroll
                for (int c = 0; c < 8; c++)
                    acc[r][c] = fmaf(av[r][kk], wf[c], acc[r][c]);
        }
    }
    float al[8], ar[8];
    #pragma unroll
    for (int c = 0; c < 8; c++) { al[c] = attn_l[c0 + c]; ar[c] = attn_r[c0 + c]; }
    int head = cg >> 3;
    #pragma unroll
    for (int r = 0; r < 4; r++) {
        int n = base + r0 + r;
        float pel = 0.f, per = 0.f;
        #pragma unroll
        for (int c = 0; c < 8; c++) {
            pel = fmaf(acc[r][c], al[c], pel);
            per = fmaf(acc[r][c], ar[c], per);
        }
        if (n < N_NODES) {
            float4 lo = {acc[r][0], acc[r][1], acc[r][2], acc[r][3]};
            float4 hi = {acc[r][4], acc[r][5], acc[r][6], acc[r][7]};
            *(float4*)(h + (size_t)n * HD + c0) = lo;
            *(float4*)(h + (size_t)n * HD + c0 + 4) = hi;
        }
        #pragma unroll
        for (int off = 1; off < 8; off <<= 1) {
            pel += __shfl_xor(pel, off, 64);
            per += __shfl_xor(per, off, 64);
        }
        if ((cg & 7) == 0 && n < N_NODES) {
            el[n * 2 + head] = pel;
            er[n * 2 + head] = per;
        }
    }
}

__global__ __launch_bounds__(256) void repr_embed_h(
        const float* __restrict__ emb, const int* __restrict__ Z,
        const float* __restrict__ fc_w, const float* __restrict__ attn_l,
        const float* __restrict__ attn_r,
        float* __restrict__ x, float* __restrict__ h,
        float* __restrict__ el, float* __restrict__ er) {
    __shared__ float bufA[TN * XLD];
    int base = blockIdx.x * TN, tid = threadIdx.x;
    int row = tid >> 2;
    int c0 = (tid & 3) << 4;
    int n = base + row;
    int z = (n < N_NODES) ? Z[n] : 0;
    const float* ep = emb + (size_t)z * D_DIM + c0;
    float* bp = bufA + row * XLD + c0;
    #pragma unroll
    for (int j = 0; j < 4; j++) {
        float4 v = *(const float4*)(ep + j * 4);
        *(float4*)(bp + j * 4) = v;
        if (n < N_NODES) *(float4*)(x + (size_t)n * D_DIM + c0 + j * 4) = v;
    }
    __syncthreads();
    gemm_h(base, tid, bufA, fc_w, attn_l, attn_r, h, el, er);
}

__global__ __launch_bounds__(256) void repr_mlp_h(
        const float* __restrict__ agg,
        const float* __restrict__ w1, const float* __restrict__ b1,
        const float* __restrict__ w2, const float* __restrict__ b2,
        const float* __restrict__ fc_w, const float* __restrict__ attn_l,
        const float* __restrict__ attn_r,
        float* __restrict__ x, float* __restrict__ h,
        float* __restrict__ el, float* __restrict__ er) {
    __shared__ float bufA[TN * TLD];
    __shared__ float v1s[TN * XLD];
    int base = blockIdx.x * TN, tid = threadIdx.x;
    load_ssp_agg(base, tid, agg, bufA);
    __syncthreads();
    gemm_mlp(base, tid, w1, b1, w2, b2, x, bufA, v1s);
    gemm_h(base, tid, bufA, fc_w, attn_l, attn_r, h, el, er);
}

__global__ __launch_bounds__(256) void repr_mlp_out(
        const float* __restrict__ agg,
        const float* __restrict__ w1, const float* __restrict__ b1,
        const float* __restrict__ w2, const float* __restrict__ b2,
        const float* __restrict__ ow1, const float* __restrict__ ob1,
        const float* __restrict__ ow2, const float* __restrict__ ob2,
        float* __restrict__ x, float* __restrict__ hh) {
    __shared__ float bufA[TN * TLD];
    __shared__ float v1s[TN * XLD];
    int base = blockIdx.x * TN, tid = threadIdx.x;
    load_ssp_agg(base, tid, agg, bufA);
    __syncthreads();
    gemm_mlp(base, tid, w1, b1, w2, b2, x, bufA, v1s);
    const int rg = tid >> 4, cg = tid & 15;
    const int r0 = rg * 4, c0 = cg * 8;
    float acc[4][8];
    #pragma unroll
    for (int r = 0; r < 4; r++)
        #pragma unroll
        for (int c = 0; c < 8; c++) acc[r][c] = 0.f;
    for (int k0 = 0; k0 < 64; k0 += 4) {
        float av[4][4];
        #pragma unroll
        for (int r = 0; r < 4; r++)
            *(float4*)av[r] = *(const float4*)&bufA[(r0 + r) * XLD + k0];
        #pragma unroll
        for (int kk = 0; kk < 4; kk++) {
            float4 w0 = *(const float4*)(ow1 + (k0 + kk) * 128 + c0);
            float4 w1v = *(const float4*)(ow1 + (k0 + kk) * 128 + c0 + 4);
            float wf[8] = {w0.x, w0.y, w0.z, w0.w, w1v.x, w1v.y, w1v.z, w1v.w};
            #pragma unroll
            for (int r = 0; r < 4; r++)
                #pragma unroll
                for (int c = 0; c < 8; c++)
                    acc[r][c] = fmaf(av[r][kk], wf[c], acc[r][c]);
        }
    }
    float o1[8], w2c[8];
    #pragma unroll
    for (int c = 0; c < 8; c++) { o1[c] = ob1[c0 + c]; w2c[c] = ow2[c0 + c]; }
    #pragma unroll
    for (int r = 0; r < 4; r++) {
        int n = base + r0 + r;
        float s = 0.f;
        #pragma unroll
        for (int c = 0; c < 8; c++)
            s = fmaf(sspf(acc[r][c] + o1[c]), w2c[c], s);
        #pragma unroll
        for (int off = 1; off < 16; off <<= 1)
            s += __shfl_xor(s, off, 64);
        if (cg == 0 && n < N_NODES) hh[n] = s + ob2[0];
    }
}

// ------------- softmax denominators (no max subtraction; exact alpha after divide) -------------
// md[d] = {1/denom0, 1/denom1}; one quarter-wave (16 lanes) per dst node; zeroes agg row
__global__ void repr_alpha(const int* __restrict__ ssrc_f, const int* __restrict__ rowptr,
                           const float* __restrict__ el, const float* __restrict__ er,
                           float2* __restrict__ md, float* __restrict__ agg) {
    int t = blockIdx.x * 256 + threadIdx.x;
    int d = t >> 4;
    int lane16 = t & 15;
    if (d >= N_NODES) return;
    float4 z = make_float4(0.f, 0.f, 0.f, 0.f);
    float4* ar = (float4*)(agg + (size_t)d * HD);
    ar[lane16 * 2] = z;
    ar[lane16 * 2 + 1] = z;
    int rs = rowptr[d];
    int re = (d == N_NODES - 1) ? N_EDGES : rowptr[d + 1];
    float2 erd = *(const float2*)&er[2 * d];
    float s0 = 0.f, s1 = 0.f;
    for (int i = rs + lane16; i < re; i += 16) {
        int s = ssrc_f[i];
        float2 a = *(const float2*)&el[2 * s];
        float v0 = a.x + erd.x; v0 = v0 >= 0.f ? v0 : 0.2f * v0;
        float v1 = a.y + erd.y; v1 = v1 >= 0.f ? v1 : 0.2f * v1;
        s0 += __expf(v0);
        s1 += __expf(v1);
    }
    #pragma unroll
    for (int off = 8; off > 0; off >>= 1) {
        s0 += __shfl_xor(s0, off, 64);
        s1 += __shfl_xor(s1, off, 64);
    }
    if (lane16 == 0) md[d] = make_float2(1.f / s0, 1.f / s1);
}

// ------------- fused filter-net (MFMA) + message + segmented-reduce scatter -------------
#define TILE2 128
#define GS_LD 72        // shorts per gs row (144 B)
#define HID_LD 136      // shorts per hid row (272 B)
#define MSGW 68         // fp32 msg leading dim (one 64-col head half)
#define HID_OFF 18432   // bytes: gs region = 128*72*2
// LDS main = 18432 + 128*136*2 = 53248; msg half [128][68] fp32 = 34816 aliased at 0

__global__ __launch_bounds__(256) void repr_msg(
    const int* __restrict__ ssrc2, const int* __restrict__ sdst2,
    const float* __restrict__ r2, const int* __restrict__ ecount,
    const float* __restrict__ el, const float* __restrict__ er,
    const float2* __restrict__ md,
    const float* __restrict__ h,
    const float* __restrict__ offs, const float* __restrict__ widths,
    const short* __restrict__ w1t, const float* __restrict__ b1,
    const short* __restrict__ w2t, const float* __restrict__ b2,
    float* __restrict__ agg)
{
    __shared__ __attribute__((aligned(16))) char lds_main[53248];
    __shared__ float r_s[TILE2];
    __shared__ float scale_s[TILE2][2];
    __shared__ int src_s[TILE2], dst_s[TILE2];
    __shared__ int seg_start_s[TILE2];
    __shared__ unsigned long long smask_s[2];
    __shared__ int nseg_s;
    __shared__ float off_s[G_GAUSS], coef_s[G_GAUSS];

    int EC = ecount[0];
    int base = blockIdx.x * TILE2;
    if (base >= EC) return;
    int tid = threadIdx.x;
    int lane = tid & 63;
    int w = tid >> 6;
    int l15 = lane & 15;
    int q = lane >> 4;
    int wbase = w * 32;

    bf16x8 bf1[2][2], bf2[2][4];
    float b1c[2], b2c[2];
    #pragma unroll
    for (int nt = 0; nt < 2; nt++) {
        int n = wbase + nt * 16 + l15;
        b1c[nt] = b1[n];
        b2c[nt] = b2[n];
        #pragma unroll
        for (int c = 0; c < 2; c++)
            bf1[nt][c] = *(const bf16x8*)(w1t + n * 64 + c * 32 + q * 8);
        #pragma unroll
        for (int c = 0; c < 4; c++)
            bf2[nt][c] = *(const bf16x8*)(w2t + n * 128 + c * 32 + q * 8);
    }

    if (tid < G_GAUSS) {
        float ww = widths[tid];
        off_s[tid] = offs[tid];
        coef_s[tid] = -0.5f / (ww * ww);
    }
    if (tid < TILE2) {
        int i = base + tid;
        int d, sn;
        float sc0, sc1, rr;
        if (i < EC) {
            sn = ssrc2[i]; d = sdst2[i];
            rr = r2[i];
            float C = 0.5f * (__cosf(rr * PI_OVER_8) + 1.f);
            float2 a = *(const float2*)&el[2 * sn];
            float2 b = *(const float2*)&er[2 * d];
            float2 rd = md[d];
            float v0 = a.x + b.x; v0 = v0 >= 0.f ? v0 : 0.2f * v0;
            float v1 = a.y + b.y; v1 = v1 >= 0.f ? v1 : 0.2f * v1;
            sc0 = C * __expf(v0) * rd.x;
            sc1 = C * __expf(v1) * rd.y;
        } else {
            sn = 0; d = -1; rr = 0.f; sc0 = 0.f; sc1 = 0.f;
        }
        src_s[tid] = sn; dst_s[tid] = d;
        r_s[tid] = rr;
        scale_s[tid][0] = sc0; scale_s[tid][1] = sc1;
    }
    __syncthreads();

    // segment detection part 1 (waves 0,1) — ballots to LDS
    if (tid < TILE2) {
        int d = dst_s[tid];
        bool flag = (tid == 0) || (dst_s[tid - 1] != d);
        unsigned long long mask = __ballot(flag);
        if (lane == 0) smask_s[w] = mask;
    }
    // gaussian tile -> bf16 LDS [128][GS_LD], K padded 50->64 (shorts 64..71 unused)
    {
        int row = tid >> 1;
        int c0 = (tid & 1) << 5;       // shorts 0 or 32
        float rr = r_s[row];
        unsigned int pk[16];
        #pragma unroll
        for (int jj = 0; jj < 16; jj++) {
            int k0 = c0 + jj * 2;
            float g0 = 0.f, g1 = 0.f;
            if (k0 < G_GAUSS)     { float dr = rr - off_s[k0];     g0 = __expf(coef_s[k0] * dr * dr); }
            if (k0 + 1 < G_GAUSS) { float dr = rr - off_s[k0 + 1]; g1 = __expf(coef_s[k0 + 1] * dr * dr); }
            pk[jj] = (unsigned int)f2bf(g0) | ((unsigned int)f2bf(g1) << 16);
        }
        char* gp = lds_main + row * (GS_LD * 2) + c0 * 2;
        *(uint4*)gp        = *(uint4*)&pk[0];
        *(uint4*)(gp + 16) = *(uint4*)&pk[4];
        *(uint4*)(gp + 32) = *(uint4*)&pk[8];
        *(uint4*)(gp + 48) = *(uint4*)&pk[12];
    }
    __syncthreads();

    // segment detection part 2 — positions (read-only consumers come after later barriers)
    if (tid < TILE2) {
        bool flag = (tid == 0) || (dst_s[tid - 1] != dst_s[tid]);
        if (flag) {
            int pos = __popcll(smask_s[w] & ((1ull << lane) - 1ull));
            if (w == 1) pos += __popcll(smask_s[0]);
            seg_start_s[pos] = tid;
        }
        if (tid == 0) nseg_s = __popcll(smask_s[0]) + __popcll(smask_s[1]);
    }

    // stage 1 MFMA: hid(128x128) = gs(128x64bf16) @ W1(64x128bf16)
    const short* gs_sh = (const short*)lds_main;
    f32x4 acc1[8][2];
    #pragma unroll
    for (int mt = 0; mt < 8; mt++)
        #pragma unroll
        for (int nt = 0; nt < 2; nt++)
            acc1[mt][nt] = (f32x4){0.f, 0.f, 0.f, 0.f};
    #pragma unroll
    for (int mt = 0; mt < 8; mt++) {
        int m = mt * 16 + l15;
        bf16x8 a0 = *(const bf16x8*)(gs_sh + m * GS_LD + q * 8);
        bf16x8 a1 = *(const bf16x8*)(gs_sh + m * GS_LD + 32 + q * 8);
        #pragma unroll
        for (int nt = 0; nt < 2; nt++) {
            acc1[mt][nt] = __builtin_amdgcn_mfma_f32_16x16x32_bf16(a0, bf1[nt][0], acc1[mt][nt], 0, 0, 0);
            acc1[mt][nt] = __builtin_amdgcn_mfma_f32_16x16x32_bf16(a1, bf1[nt][1], acc1[mt][nt], 0, 0, 0);
        }
    }
    short* hid_sh = (short*)(lds_main + HID_OFF);
    #pragma unroll
    for (int mt = 0; mt < 8; mt++)
        #pragma unroll
        for (int nt = 0; nt < 2; nt++) {
            int colg = wbase + nt * 16 + l15;
            #pragma unroll
            for (int rg = 0; rg < 4; rg++) {
                int row = mt * 16 + q * 4 + rg;   // C/D: col=lane&15, row=quad*4+reg
                float v = sspf_fast(acc1[mt][nt][rg] + b1c[nt]);
                hid_sh[row * HID_LD + colg] = (short)f2bf(v);
            }
        }
    __syncthreads();

    // stage 2 MFMA: wv(128x128) = hid(128x128bf16) @ W2(128x128bf16)
    f32x4 acc2[8][2];
    #pragma unroll
    for (int mt = 0; mt < 8; mt++)
        #pragma unroll
        for (int nt = 0; nt < 2; nt++)
            acc2[mt][nt] = (f32x4){0.f, 0.f, 0.f, 0.f};
    #pragma unroll
    for (int mt = 0; mt < 8; mt++) {
        int m = mt * 16 + l15;
        #pragma unroll
        for (int c = 0; c < 4; c++) {
            bf16x8 a = *(const bf16x8*)(hid_sh + m * HID_LD + c * 32 + q * 8);
            #pragma unroll
            for (int nt = 0; nt < 2; nt++)
                acc2[mt][nt] = __builtin_amdgcn_mfma_f32_16x16x32_bf16(a, bf2[nt][c], acc2[mt][nt], 0, 0, 0);
        }
    }
    __syncthreads();   // all gs/hid reads done; msg may alias lds_main

    float* msg_f = (float*)lds_main;
    // ---- phase A: head 0, cols 0..63 (waves 0,1) ----
    if (w < 2) {
        #pragma unroll
        for (int mt = 0; mt < 8; mt++)
            #pragma unroll
            for (int nt = 0; nt < 2; nt++) {
                int colg = wbase + nt * 16 + l15;          // 0..63
                #pragma unroll
                for (int rg = 0; rg < 4; rg++) {
                    int row = mt * 16 + q * 4 + rg;
                    float sc = scale_s[row][0];
                    float hv = h[(size_t)src_s[row] * HD + colg];
                    msg_f[row * MSGW + colg] = (acc2[mt][nt][rg] + b2c[nt]) * hv * sc;
                }
            }
    }
    __syncthreads();
    {
        int nseg = nseg_s;
        int col = tid & 63;
        int sp = tid >> 6;
        for (int s = sp; s < nseg; s += 4) {
            int r0 = seg_start_s[s];
            int r1 = (s + 1 < nseg) ? seg_start_s[s + 1] : TILE2;
            int d = dst_s[r0];
            if (d < 0) continue;
            float sum = 0.f;
            for (int r = r0; r < r1; r++) sum += msg_f[r * MSGW + col];
            float* ap = &agg[(size_t)d * HD + col];
            if (s == 0 || s == nseg - 1) atomicAdd(ap, sum);
            else *ap = sum;
        }
    }
    __syncthreads();
    // ---- phase B: head 1, cols 64..127 (waves 2,3) ----
    if (w >= 2) {
        #pragma unroll
        for (int mt = 0; mt < 8; mt++)
            #pragma unroll
            for (int nt = 0; nt < 2; nt++) {
                int colg = wbase + nt * 16 + l15;          // 64..127
                #pragma unroll
                for (int rg = 0; rg < 4; rg++) {
                    int row = mt * 16 + q * 4 + rg;
                    float sc = scale_s[row][1];
                    float hv = h[(size_t)src_s[row] * HD + colg];
                    msg_f[row * MSGW + (colg - 64)] = (acc2[mt][nt][rg] + b2c[nt]) * hv * sc;
                }
            }
    }
    __syncthreads();
    {
        int nseg = nseg_s;
        int col = tid & 63;
        int sp = tid >> 6;
        for (int s = sp; s < nseg; s += 4) {
            int r0 = seg_start_s[s];
            int r1 = (s + 1 < nseg) ? seg_start_s[s + 1] : TILE2;
            int d = dst_s[r0];
            if (d < 0) continue;
            float sum = 0.f;
            for (int r = r0; r < r1; r++) sum += msg_f[r * MSGW + col];
            float* ap = &agg[(size_t)d * HD + 64 + col];
            if (s == 0 || s == nseg - 1) atomicAdd(ap, sum);
            else *ap = sum;
        }
    }
}

// ------------- graph segment-sum with LDS privatization -> d_out directly -------------
__global__ void repr_gsum(const float* __restrict__ hh, const int* __restrict__ gids,
                          float* __restrict__ dout) {
    __shared__ float bins[B_GRAPHS];
    int t = threadIdx.x;
    if (t < B_GRAPHS) bins[t] = 0.f;
    __syncthreads();
    int i = blockIdx.x * 256 + t;
    if (i < N_NODES) atomicAdd(&bins[gids[i]], hh[i]);
    __syncthreads();
    if (t < B_GRAPHS && bins[t] != 0.f) atomicAdd(&dout[t], bins[t]);
}

extern "C" void kernel_launch(void* const* d_in, const int* in_sizes, int n_in,
                              void* d_out, int out_size, void* d_ws, size_t ws_size,
                              hipStream_t stream) {
    (void)in_sizes; (void)n_in; (void)out_size; (void)ws_size;
    const float* R      = (const float*)d_in[0];
    const int*   Z      = (const int*)d_in[1];
    const int*   src    = (const int*)d_in[2];
    const int*   dst    = (const int*)d_in[3];
    const int*   gids   = (const int*)d_in[4];
    const float* emb    = (const float*)d_in[5];
    const float* offs   = (const float*)d_in[6];
    const float* widths = (const float*)d_in[7];
    const float* fc_w   = (const float*)d_in[8];
    const float* attn_l = (const float*)d_in[9];
    const float* attn_r = (const float*)d_in[10];
    const float* fw1    = (const float*)d_in[11];
    const float* fb1    = (const float*)d_in[12];
    const float* fw2    = (const float*)d_in[13];
    const float* fb2    = (const float*)d_in[14];
    const float* mw1    = (const float*)d_in[15];
    const float* mb1    = (const float*)d_in[16];
    const float* mw2    = (const float*)d_in[17];
    const float* mb2    = (const float*)d_in[18];
    const float* ow1    = (const float*)d_in[19];
    const float* ob1    = (const float*)d_in[20];
    const float* ow2    = (const float*)d_in[21];
    const float* ob2    = (const float*)d_in[22];

    char* p = (char*)d_ws;
    float* x      = (float*)p; p += (size_t)N_NODES * 64 * 4;
    float* h      = (float*)p; p += (size_t)N_NODES * 128 * 4;
    float* el     = (float*)p; p += (size_t)N_NODES * 2 * 4;
    float* er     = (float*)p; p += (size_t)N_NODES * 2 * 4;
    float2* md    = (float2*)p; p += (size_t)N_NODES * 8;
    float* agg    = (float*)p; p += (size_t)N_NODES * 128 * 4;
    int*   ssrc_f = (int*)p;   p += (size_t)N_EDGES * 4;
    int*   sdst_f = (int*)p;   p += (size_t)N_EDGES * 4;
    int*   rowptr = (int*)p;   p += (size_t)N_NODES * 4;
    int*   ssrc2  = (int*)p;   p += (size_t)N_EDGES * 4;
    int*   sdst2  = (int*)p;   p += (size_t)N_EDGES * 4;
    float* r2     = (float*)p; p += (size_t)N_EDGES * 4;
    float* r_full = (float*)p; p += (size_t)N_EDGES * 4;
    float* hh     = (float*)p; p += (size_t)N_NODES * 4;
    short* w1t    = (short*)p; p += (size_t)L_LAYERS * 8192 * 2;
    short* w2t    = (short*)p; p += (size_t)L_LAYERS * 16384 * 2;
    int*   bsumA  = (int*)p;   p += 1024;
    int*   bprefA = (int*)p;   p += 1024;
    int*   bsumB  = (int*)p;   p += 1024;
    int*   bprefB = (int*)p;   p += 1024;
    int*   ecF    = (int*)p;   p += 256;
    int*   ecS    = (int*)p;   p += 256;
    // scan temporaries aliased into x (x written by repr_embed_h, strictly after
    // repr_scatter in stream order):
    int* count_f = (int*)x;
    int* excl_f  = (int*)((char*)x + 256 * 1024);
    int* cur_f   = (int*)((char*)x + 512 * 1024);
    int* count_s = (int*)((char*)x + 768 * 1024);
    int* excl_s  = (int*)((char*)x + 1024 * 1024);
    int* cur_s   = (int*)((char*)x + 1280 * 1024);

    // one-time prep: weight transpose + zero counters + zero d_out
    repr_prep<<<(PREP_W + 2 * N_NODES + B_GRAPHS + 255) / 256, 256, 0, stream>>>(
        fw1, fw2, w1t, w2t, count_f, count_s, (float*)d_out);
    repr_hist<<<N_EDGES / 256, 256, 0, stream>>>(R, src, dst, count_f, count_s, r_full);
    repr_scanA2<<<2 * NCHUNK, 256, 0, stream>>>(count_f, excl_f, bsumA,
                                                count_s, excl_s, bsumB);
    repr_scanB2<<<2, 256, 0, stream>>>(bsumA, bprefA, ecF, bsumB, bprefB, ecS);
    repr_scanC2<<<2 * NCHUNK, 256, 0, stream>>>(excl_f, bprefA, cur_f, rowptr,
                                                excl_s, bprefB, cur_s);
    repr_scatter<<<N_EDGES / 256, 256, 0, stream>>>(
        r_full, src, dst, cur_f, cur_s, ssrc_f, sdst_f, ssrc2, sdst2, r2);

    repr_embed_h<<<NBLK, 256, 0, stream>>>(
        emb, Z, fc_w, attn_l, attn_r, x, h, el, er);

    for (int l = 0; l < L_LAYERS; l++) {
        repr_alpha<<<(N_NODES * 16 + 255) / 256, 256, 0, stream>>>(
            ssrc_f, rowptr, el, er, md, agg);
        repr_msg<<<(N_EDGES + TILE2 - 1) / TILE2, 256, 0, stream>>>(
            ssrc2, sdst2, r2, ecS, el, er, md, h, offs, widths,
            w1t + (size_t)l * 8192, fb1 + (size_t)l * HID_DIM,
            w2t + (size_t)l * 16384, fb2 + (size_t)l * HD, agg);
        if (l < L_LAYERS - 1) {
            repr_mlp_h<<<NBLK, 256, 0, stream>>>(
                agg, mw1 + (size_t)l * 128 * 64, mb1 + l * 64,
                mw2 + (size_t)l * 64 * 64, mb2 + l * 64,
                fc_w + (size_t)(l + 1) * 64 * 128, attn_l + (l + 1) * 128,
                attn_r + (l + 1) * 128, x, h, el, er);
        } else {
            repr_mlp_out<<<NBLK, 256, 0, stream>>>(
                agg, mw1 + (size_t)l * 128 * 64, mb1 + l * 64,
                mw2 + (size_t)l * 64 * 64, mb2 + l * 64,
                ow1, ob1, ow2, ob2, x, hh);
        }
    }
    repr_gsum<<<NCHUNK, 256, 0, stream>>>(hh, gids, (float*)d_out);
}

// Round 11
// 778.301 us; speedup vs baseline: 1.1878x; 1.1878x over previous
//
#include <hip/hip_runtime.h>
#include <stdint.h>

#define N_NODES 50000
#define N_EDGES 800000
#define B_GRAPHS 64
#define D_DIM 64
#define HD 128
#define G_GAUSS 50
#define HID_DIM 128
#define L_LAYERS 3
#define LN2 0.69314718055994530942f
#define PI_OVER_8 0.39269908169872414f
#define NCHUNK 196            // ceil(50000/256)

#define TN 64                 // nodes per node-GEMM block
#define TLD 132               // fp32 LDS leading dim for 128-wide tiles
#define XLD 68                // fp32 LDS leading dim for 64-wide tiles
#define NBLK ((N_NODES + TN - 1) / TN)   // 782

typedef __attribute__((ext_vector_type(8))) short bf16x8;
typedef __attribute__((ext_vector_type(4))) float f32x4;

__device__ __forceinline__ float sspf(float x) {
    float ax = fabsf(x);
    return fmaxf(x, 0.f) + __logf(1.f + __expf(-ax)) - LN2;
}
// non-stable variant: valid for |x| < ~80 (hid pre-activations are |x|<~5)
__device__ __forceinline__ float sspf_fast(float x) {
    return __logf(1.f + __expf(x)) - LN2;
}
__device__ __forceinline__ unsigned short f2bf(float f) {
    union { float f; unsigned int i; } v; v.f = f;
    unsigned int u = v.i;
    return (unsigned short)((u + 0x7FFFu + ((u >> 16) & 1u)) >> 16);
}

// ------------- one-time: bf16 transposed weights + zero counters/out -------------
#define PREP_W (L_LAYERS * 24576)     // 73728
__global__ void repr_prep(const float* __restrict__ fw1, const float* __restrict__ fw2,
                          short* __restrict__ w1t, short* __restrict__ w2t,
                          int* __restrict__ count_f, int* __restrict__ count_s,
                          float* __restrict__ dout) {
    int i = blockIdx.x * 256 + threadIdx.x;
    if (i < PREP_W) {
        int l = i / 24576, rem = i % 24576;
        if (rem < 8192) {
            int n = rem >> 6, k = rem & 63;
            float v = (k < G_GAUSS) ? fw1[(size_t)l * G_GAUSS * HID_DIM + k * HID_DIM + n] : 0.f;
            w1t[(size_t)l * 8192 + rem] = (short)f2bf(v);
        } else {
            int r2 = rem - 8192;
            int n = r2 >> 7, k = r2 & 127;
            float v = fw2[(size_t)l * HID_DIM * HD + k * HD + n];
            w2t[(size_t)l * 16384 + r2] = (short)f2bf(v);
        }
    } else {
        int j = i - PREP_W;
        if (j < N_NODES) count_f[j] = 0;
        else if (j < 2 * N_NODES) count_s[j - N_NODES] = 0;
        else if (j < 2 * N_NODES + B_GRAPHS) dout[j - 2 * N_NODES] = 0.f;
    }
}

// ------------- histograms (+ store r per edge) -------------
__global__ void repr_hist(const float* __restrict__ R,
                          const int* __restrict__ src, const int* __restrict__ dst,
                          int* __restrict__ count_f, int* __restrict__ count_s,
                          float* __restrict__ r_full) {
    int e = blockIdx.x * blockDim.x + threadIdx.x;
    if (e >= N_EDGES) return;
    int s = src[e], d = dst[e];
    atomicAdd(&count_f[d], 1);
    float dx = R[3*s+0] - R[3*d+0];
    float dy = R[3*s+1] - R[3*d+1];
    float dz = R[3*s+2] - R[3*d+2];
    float r = sqrtf(dx*dx + dy*dy + dz*dz);
    r_full[e] = r;
    if (r < 8.0f) atomicAdd(&count_s[d], 1);
}

// ------------- dual 2-level exclusive scan over 50000 counts -------------
__global__ void repr_scanA2(const int* __restrict__ cntA, int* __restrict__ exclA,
                            int* __restrict__ bsumA,
                            const int* __restrict__ cntB, int* __restrict__ exclB,
                            int* __restrict__ bsumB) {
    __shared__ int tmp[256];
    int t = threadIdx.x, b = blockIdx.x;
    const int* cnt; int* excl; int* bsum; int bb;
    if (b < NCHUNK) { cnt = cntA; excl = exclA; bsum = bsumA; bb = b; }
    else            { cnt = cntB; excl = exclB; bsum = bsumB; bb = b - NCHUNK; }
    int i = bb * 256 + t;
    int v = (i < N_NODES) ? cnt[i] : 0;
    tmp[t] = v; __syncthreads();
    for (int off = 1; off < 256; off <<= 1) {
        int add = (t >= off) ? tmp[t - off] : 0;
        __syncthreads();
        tmp[t] += add;
        __syncthreads();
    }
    if (i < N_NODES) excl[i] = tmp[t] - v;
    if (t == 255) bsum[bb] = tmp[255];
}
__global__ void repr_scanB2(const int* __restrict__ bsumA, int* __restrict__ bprefA,
                            int* __restrict__ ecA,
                            const int* __restrict__ bsumB, int* __restrict__ bprefB,
                            int* __restrict__ ecB) {
    __shared__ int tmp[256];
    const int* bsum = blockIdx.x ? bsumB : bsumA;
    int* bpref = blockIdx.x ? bprefB : bprefA;
    int* ec = blockIdx.x ? ecB : ecA;
    int t = threadIdx.x;
    int v = (t < NCHUNK) ? bsum[t] : 0;
    tmp[t] = v; __syncthreads();
    for (int off = 1; off < 256; off <<= 1) {
        int add = (t >= off) ? tmp[t - off] : 0;
        __syncthreads();
        tmp[t] += add;
        __syncthreads();
    }
    if (t < NCHUNK) bpref[t] = tmp[t] - v;
    if (t == 255) ec[0] = tmp[255];
}
__global__ void repr_scanC2(const int* __restrict__ exclA, const int* __restrict__ bprefA,
                            int* __restrict__ curA, int* __restrict__ rowptr,
                            const int* __restrict__ exclB, const int* __restrict__ bprefB,
                            int* __restrict__ curB) {
    int b = blockIdx.x;
    if (b < NCHUNK) {
        int i = b * 256 + threadIdx.x;
        if (i < N_NODES) { int v = exclA[i] + bprefA[b]; curA[i] = v; rowptr[i] = v; }
    } else {
        int i = (b - NCHUNK) * 256 + threadIdx.x;
        if (i < N_NODES) curB[i] = exclB[i] + bprefB[b - NCHUNK];
    }
}

// ------------- scatter: full dst-sorted list + survivor dst-sorted list -------------
__global__ void repr_scatter(const float* __restrict__ r_full,
                             const int* __restrict__ src, const int* __restrict__ dst,
                             int* __restrict__ cur_f, int* __restrict__ cur_s,
                             int* __restrict__ ssrc_f, int* __restrict__ sdst_f,
                             int* __restrict__ ssrc2, int* __restrict__ sdst2,
                             float* __restrict__ r2) {
    int e = blockIdx.x * blockDim.x + threadIdx.x;
    if (e >= N_EDGES) return;
    int s = src[e], d = dst[e];
    float r = r_full[e];
    int pos = atomicAdd(&cur_f[d], 1);
    ssrc_f[pos] = s; sdst_f[pos] = d;
    if (r < 8.0f) {
        int p2 = atomicAdd(&cur_s[d], 1);
        ssrc2[p2] = s; sdst2[p2] = d; r2[p2] = r;
    }
}

// ================= tiled fp32 node GEMMs (64 nodes / block, 256 threads) =================

__device__ __forceinline__ void load_ssp_agg(int base, int tid,
        const float* __restrict__ agg, float* __restrict__ bufA) {
    int row = tid >> 2;
    int c0 = (tid & 3) << 5;
    const float* ap = agg + (size_t)(base + row) * HD + c0;
    float* tp = bufA + row * TLD + c0;
    #pragma unroll
    for (int j = 0; j < 8; j++) {
        float4 v = *(const float4*)(ap + j * 4);
        tp[j*4+0] = sspf(v.x); tp[j*4+1] = sspf(v.y);
        tp[j*4+2] = sspf(v.z); tp[j*4+3] = sspf(v.w);
    }
}

__device__ __forceinline__ void gemm_mlp(int base, int tid,
        const float* __restrict__ w1, const float* __restrict__ b1,
        const float* __restrict__ w2, const float* __restrict__ b2,
        float* __restrict__ x, float* __restrict__ bufA, float* __restrict__ v1s)
{
    const int rg = tid >> 4, cg = tid & 15;
    const int r0 = rg * 4, c0 = cg * 4;
    float acc[4][4];
    #pragma unroll
    for (int r = 0; r < 4; r++)
        #pragma unroll
        for (int c = 0; c < 4; c++) acc[r][c] = 0.f;
    for (int k0 = 0; k0 < 128; k0 += 4) {
        float av[4][4];
        #pragma unroll
        for (int r = 0; r < 4; r++)
            *(float4*)av[r] = *(const float4*)&bufA[(r0 + r) * TLD + k0];
        #pragma unroll
        for (int kk = 0; kk < 4; kk++) {
            float4 wv = *(const float4*)(w1 + (k0 + kk) * 64 + c0);
            float wf[4] = {wv.x, wv.y, wv.z, wv.w};
            #pragma unroll
            for (int r = 0; r < 4; r++)
                #pragma unroll
                for (int c = 0; c < 4; c++)
                    acc[r][c] = fmaf(av[r][kk], wf[c], acc[r][c]);
        }
    }
    {
        float4 bv = *(const float4*)(b1 + c0);
        float ba[4] = {bv.x, bv.y, bv.z, bv.w};
        #pragma unroll
        for (int r = 0; r < 4; r++)
            #pragma unroll
            for (int c = 0; c < 4; c++)
                v1s[(r0 + r) * XLD + c0 + c] = sspf(acc[r][c] + ba[c]);
    }
    __syncthreads();
    float acc2[4][4];
    #pragma unroll
    for (int r = 0; r < 4; r++)
        #pragma unroll
        for (int c = 0; c < 4; c++) acc2[r][c] = 0.f;
    for (int k0 = 0; k0 < 64; k0 += 4) {
        float av[4][4];
        #pragma unroll
        for (int r = 0; r < 4; r++)
            *(float4*)av[r] = *(const float4*)&v1s[(r0 + r) * XLD + k0];
        #pragma unroll
        for (int kk = 0; kk < 4; kk++) {
            float4 wv = *(const float4*)(w2 + (k0 + kk) * 64 + c0);
            float wf[4] = {wv.x, wv.y, wv.z, wv.w};
            #pragma unroll
            for (int r = 0; r < 4; r++)
                #pragma unroll
                for (int c = 0; c < 4; c++)
                    acc2[r][c] = fmaf(av[r][kk], wf[c], acc2[r][c]);
        }
    }
    {
        float4 bv = *(const float4*)(b2 + c0);
        #pragma unroll
        for (int r = 0; r < 4; r++) {
            int n = base + r0 + r;
            float4 xv = *(const float4*)(x + (size_t)n * 64 + c0);
            float4 o;
            o.x = acc2[r][0] + bv.x + xv.x;
            o.y = acc2[r][1] + bv.y + xv.y;
            o.z = acc2[r][2] + bv.z + xv.z;
            o.w = acc2[r][3] + bv.w + xv.w;
            *(float4*)&bufA[(r0 + r) * XLD + c0] = o;
            if (n < N_NODES) *(float4*)(x + (size_t)n * 64 + c0) = o;
        }
    }
    __syncthreads();
}

__device__ __forceinline__ void gemm_h(int base, int tid,
        const float* __restrict__ bufA,
        const float* __restrict__ fc_w, const float* __restrict__ attn_l,
        const float* __restrict__ attn_r,
        float* __restrict__ h, float* __restrict__ el, float* __restrict__ er)
{
    const int rg = tid >> 4, cg = tid & 15;
    const int r0 = rg * 4, c0 = cg * 8;
    float acc[4][8];
    #pragma unroll
    for (int r = 0; r < 4; r++)
        #pragma unroll
        for (int c = 0; c < 8; c++) acc[r][c] = 0.f;
    for (int k0 = 0; k0 < 64; k0 += 4) {
        float av[4][4];
        #pragma unroll
        for (int r = 0; r < 4; r++)
            *(float4*)av[r] = *(const float4*)&bufA[(r0 + r) * XLD + k0];
        #pragma unroll
        for (int kk = 0; kk < 4; kk++) {
            float4 w0 = *(const float4*)(fc_w + (k0 + kk) * 128 + c0);
            float4 w1v = *(const float4*)(fc_w + (k0 + kk) * 128 + c0 + 4);
            float wf[8] = {w0.x, w0.y, w0.z, w0.w, w1v.x, w1v.y, w1v.z, w1v.w};
            #pragma unroll
            for (int r = 0; r < 4; r++)
                #pragma unroll
                for (int c = 0; c < 8; c++)
                    acc[r][c] = fmaf(av[r][kk], wf[c], acc[r][c]);
        }
    }
    float al[8], ar[8];
    #pragma unroll
    for (int c = 0; c < 8; c++) { al[c] = attn_l[c0 + c]; ar[c] = attn_r[c0 + c]; }
    int head = cg >> 3;
    #pragma unroll
    for (int r = 0; r < 4; r++) {
        int n = base + r0 + r;
        float pel = 0.f, per = 0.f;
        #pragma unroll
        for (int c = 0; c < 8; c++) {
            pel = fmaf(acc[r][c], al[c], pel);
            per = fmaf(acc[r][c], ar[c], per);
        }
        if (n < N_NODES) {
            float4 lo = {acc[r][0], acc[r][1], acc[r][2], acc[r][3]};
            float4 hi = {acc[r][4], acc[r][5], acc[r][6], acc[r][7]};
            *(float4*)(h + (size_t)n * HD + c0) = lo;
            *(float4*)(h + (size_t)n * HD + c0 + 4) = hi;
        }
        #pragma unroll
        for (int off = 1; off < 8; off <<= 1) {
            pel += __shfl_xor(pel, off, 64);
            per += __shfl_xor(per, off, 64);
        }
        if ((cg & 7) == 0 && n < N_NODES) {
            el[n * 2 + head] = pel;
            er[n * 2 + head] = per;
        }
    }
}

__global__ __launch_bounds__(256) void repr_embed_h(
        const float* __restrict__ emb, const int* __restrict__ Z,
        const float* __restrict__ fc_w, const float* __restrict__ attn_l,
        const float* __restrict__ attn_r,
        float* __restrict__ x, float* __restrict__ h,
        float* __restrict__ el, float* __restrict__ er) {
    __shared__ float bufA[TN * XLD];
    int base = blockIdx.x * TN, tid = threadIdx.x;
    int row = tid >> 2;
    int c0 = (tid & 3) << 4;
    int n = base + row;
    int z = (n < N_NODES) ? Z[n] : 0;
    const float* ep = emb + (size_t)z * D_DIM + c0;
    float* bp = bufA + row * XLD + c0;
    #pragma unroll
    for (int j = 0; j < 4; j++) {
        float4 v = *(const float4*)(ep + j * 4);
        *(float4*)(bp + j * 4) = v;
        if (n < N_NODES) *(float4*)(x + (size_t)n * D_DIM + c0 + j * 4) = v;
    }
    __syncthreads();
    gemm_h(base, tid, bufA, fc_w, attn_l, attn_r, h, el, er);
}

__global__ __launch_bounds__(256) void repr_mlp_h(
        const float* __restrict__ agg,
        const float* __restrict__ w1, const float* __restrict__ b1,
        const float* __restrict__ w2, const float* __restrict__ b2,
        const float* __restrict__ fc_w, const float* __restrict__ attn_l,
        const float* __restrict__ attn_r,
        float* __restrict__ x, float* __restrict__ h,
        float* __restrict__ el, float* __restrict__ er) {
    __shared__ float bufA[TN * TLD];
    __shared__ float v1s[TN * XLD];
    int base = blockIdx.x * TN, tid = threadIdx.x;
    load_ssp_agg(base, tid, agg, bufA);
    __syncthreads();
    gemm_mlp(base, tid, w1, b1, w2, b2, x, bufA, v1s);
    gemm_h(base, tid, bufA, fc_w, attn_l, attn_r, h, el, er);
}

__global__ __launch_bounds__(256) void repr_mlp_out(
        const float* __restrict__ agg,
        const float* __restrict__ w1, const float* __restrict__ b1,
        const float* __restrict__ w2, const float* __restrict__ b2,
        const float* __restrict__ ow1, const float* __restrict__ ob1,
        const float* __restrict__ ow2, const float* __restrict__ ob2,
        float* __restrict__ x, float* __restrict__ hh) {
    __shared__ float bufA[TN * TLD];
    __shared__ float v1s[TN * XLD];
    int base = blockIdx.x * TN, tid = threadIdx.x;
    load_ssp_agg(base, tid, agg, bufA);
    __syncthreads();
    gemm_mlp(base, tid, w1, b1, w2, b2, x, bufA, v1s);
    const int rg = tid >> 4, cg = tid & 15;
    const int r0 = rg * 4, c0 = cg * 8;
    float acc[4][8];
    #pragma unroll
    for (int r = 0; r < 4; r++)
        #pragma unroll
        for (int c = 0; c < 8; c++) acc[r][c] = 0.f;
    for (int k0 = 0; k0 < 64; k0 += 4) {
        float av[4][4];
        #pragma unroll
        for (int r = 0; r < 4; r++)
            *(float4*)av[r] = *(const float4*)&bufA[(r0 + r) * XLD + k0];
        #pragma unroll
        for (int kk = 0; kk < 4; kk++) {
            float4 w0 = *(const float4*)(ow1 + (k0 + kk) * 128 + c0);
            float4 w1v = *(const float4*)(ow1 + (k0 + kk) * 128 + c0 + 4);
            float wf[8] = {w0.x, w0.y, w0.z, w0.w, w1v.x, w1v.y, w1v.z, w1v.w};
            #pragma unroll
            for (int r = 0; r < 4; r++)
                #pragma unroll
                for (int c = 0; c < 8; c++)
                    acc[r][c] = fmaf(av[r][kk], wf[c], acc[r][c]);
        }
    }
    float o1[8], w2c[8];
    #pragma unroll
    for (int c = 0; c < 8; c++) { o1[c] = ob1[c0 + c]; w2c[c] = ow2[c0 + c]; }
    #pragma unroll
    for (int r = 0; r < 4; r++) {
        int n = base + r0 + r;
        float s = 0.f;
        #pragma unroll
        for (int c = 0; c < 8; c++)
            s = fmaf(sspf(acc[r][c] + o1[c]), w2c[c], s);
        #pragma unroll
        for (int off = 1; off < 16; off <<= 1)
            s += __shfl_xor(s, off, 64);
        if (cg == 0 && n < N_NODES) hh[n] = s + ob2[0];
    }
}

// ------------- softmax denominators (no max subtraction) + agg zeroing -------------
// md[d] = {1/denom0, 1/denom1}; one quarter-wave (16 lanes) per dst node
__global__ void repr_alpha(const int* __restrict__ ssrc_f, const int* __restrict__ rowptr,
                           const float* __restrict__ el, const float* __restrict__ er,
                           float2* __restrict__ md, float* __restrict__ agg) {
    int t = blockIdx.x * 256 + threadIdx.x;
    int d = t >> 4;
    int lane16 = t & 15;
    if (d >= N_NODES) return;
    float4 z = make_float4(0.f, 0.f, 0.f, 0.f);
    float4* ar = (float4*)(agg + (size_t)d * HD);
    ar[lane16 * 2] = z;
    ar[lane16 * 2 + 1] = z;
    int rs = rowptr[d];
    int re = (d == N_NODES - 1) ? N_EDGES : rowptr[d + 1];
    float2 erd = *(const float2*)&er[2 * d];
    float s0 = 0.f, s1 = 0.f;
    for (int i = rs + lane16; i < re; i += 16) {
        int s = ssrc_f[i];
        float2 a = *(const float2*)&el[2 * s];
        float v0 = a.x + erd.x; v0 = v0 >= 0.f ? v0 : 0.2f * v0;
        float v1 = a.y + erd.y; v1 = v1 >= 0.f ? v1 : 0.2f * v1;
        s0 += __expf(v0);
        s1 += __expf(v1);
    }
    #pragma unroll
    for (int off = 8; off > 0; off >>= 1) {
        s0 += __shfl_xor(s0, off, 64);
        s1 += __shfl_xor(s1, off, 64);
    }
    if (lane16 == 0) md[d] = make_float2(1.f / s0, 1.f / s1);
}

// ------------- fused filter-net (MFMA) + message + segmented-reduce scatter -------------
// TILE=64: LDS 35840 B -> 4 blocks/CU (measured round 7-9: 122 us, VALUBusy 70%).
// TILE=128 was tried (round 10): LDS 56832 -> 2 blocks/CU, occupancy 20% -> 164 us. REVERTED.
#define TILE 64
#define GS_LD 72        // shorts per gs row (144 B)
#define HID_LD 136      // shorts per hid row (272 B)
#define MSG_LD 132      // floats per msg row
#define HID_OFF 9216    // bytes: gs region = 64*72*2

__global__ __launch_bounds__(256) void repr_msg(
    const int* __restrict__ ssrc2, const int* __restrict__ sdst2,
    const float* __restrict__ r2, const int* __restrict__ ecount,
    const float* __restrict__ el, const float* __restrict__ er,
    const float2* __restrict__ md,
    const float* __restrict__ h,
    const float* __restrict__ offs, const float* __restrict__ widths,
    const short* __restrict__ w1t, const float* __restrict__ b1,
    const short* __restrict__ w2t, const float* __restrict__ b2,
    float* __restrict__ agg)
{
    __shared__ __attribute__((aligned(16))) char lds_main[33792];
    __shared__ float r_s[TILE];
    __shared__ float scale_s[TILE][2];
    __shared__ int src_s[TILE], dst_s[TILE];
    __shared__ int seg_start_s[TILE];
    __shared__ int nseg_s;
    __shared__ float off_s[G_GAUSS], coef_s[G_GAUSS];

    int EC = ecount[0];
    int base = blockIdx.x * TILE;
    if (base >= EC) return;
    int tid = threadIdx.x;
    int lane = tid & 63;
    int w = tid >> 6;
    int l15 = lane & 15;
    int q = lane >> 4;
    int wbase = w * 32;

    bf16x8 bf1[2][2], bf2[2][4];
    float b1c[2], b2c[2];
    #pragma unroll
    for (int nt = 0; nt < 2; nt++) {
        int n = wbase + nt * 16 + l15;
        b1c[nt] = b1[n];
        b2c[nt] = b2[n];
        #pragma unroll
        for (int c = 0; c < 2; c++)
            bf1[nt][c] = *(const bf16x8*)(w1t + n * 64 + c * 32 + q * 8);
        #pragma unroll
        for (int c = 0; c < 4; c++)
            bf2[nt][c] = *(const bf16x8*)(w2t + n * 128 + c * 32 + q * 8);
    }

    if (tid < G_GAUSS) {
        float ww = widths[tid];
        off_s[tid] = offs[tid];
        coef_s[tid] = -0.5f / (ww * ww);
    }
    if (tid < TILE) {
        int i = base + tid;
        int d, sn;
        float sc0, sc1, rr;
        if (i < EC) {
            sn = ssrc2[i]; d = sdst2[i];
            rr = r2[i];
            float C = 0.5f * (__cosf(rr * PI_OVER_8) + 1.f);
            float2 a = *(const float2*)&el[2 * sn];
            float2 b = *(const float2*)&er[2 * d];
            float2 rd = md[d];
            float v0 = a.x + b.x; v0 = v0 >= 0.f ? v0 : 0.2f * v0;
            float v1 = a.y + b.y; v1 = v1 >= 0.f ? v1 : 0.2f * v1;
            sc0 = C * __expf(v0) * rd.x;
            sc1 = C * __expf(v1) * rd.y;
        } else {
            sn = 0; d = -1; rr = 0.f; sc0 = 0.f; sc1 = 0.f;
        }
        src_s[tid] = sn; dst_s[tid] = d;
        r_s[tid] = rr;
        scale_s[tid][0] = sc0; scale_s[tid][1] = sc1;
        int dprev = __shfl_up(d, 1, 64);
        bool flag = (tid == 0) || (d != dprev);
        unsigned long long mask = __ballot(flag);
        if (flag) seg_start_s[__popcll(mask & ((1ull << tid) - 1ull))] = tid;
        if (tid == 0) nseg_s = (int)__popcll(mask);
    }
    __syncthreads();

    // gaussian tile -> bf16 LDS, A-layout row-major [64][GS_LD], K padded 50->64
    {
        int row = tid >> 2;
        int c16 = (tid & 3) << 4;
        float rr = r_s[row];
        unsigned int pk[8];
        #pragma unroll
        for (int jj = 0; jj < 8; jj++) {
            int k0 = c16 + jj * 2;
            float g0 = 0.f, g1 = 0.f;
            if (k0 < G_GAUSS)     { float dr = rr - off_s[k0];     g0 = __expf(coef_s[k0] * dr * dr); }
            if (k0 + 1 < G_GAUSS) { float dr = rr - off_s[k0 + 1]; g1 = __expf(coef_s[k0 + 1] * dr * dr); }
            pk[jj] = (unsigned int)f2bf(g0) | ((unsigned int)f2bf(g1) << 16);
        }
        char* gp = lds_main + row * (GS_LD * 2) + c16 * 2;
        *(uint4*)gp = *(uint4*)&pk[0];
        *(uint4*)(gp + 16) = *(uint4*)&pk[4];
    }
    __syncthreads();

    // stage 1 MFMA: hid(64x128) = gs(64x64bf16) @ W1(64x128bf16)
    const short* gs_sh = (const short*)lds_main;
    f32x4 acc1[4][2];
    #pragma unroll
    for (int mt = 0; mt < 4; mt++)
        #pragma unroll
        for (int nt = 0; nt < 2; nt++)
            acc1[mt][nt] = (f32x4){0.f, 0.f, 0.f, 0.f};
    #pragma unroll
    for (int mt = 0; mt < 4; mt++) {
        int m = mt * 16 + l15;
        bf16x8 a0 = *(const bf16x8*)(gs_sh + m * GS_LD + q * 8);
        bf16x8 a1 = *(const bf16x8*)(gs_sh + m * GS_LD + 32 + q * 8);
        #pragma unroll
        for (int nt = 0; nt < 2; nt++) {
            acc1[mt][nt] = __builtin_amdgcn_mfma_f32_16x16x32_bf16(a0, bf1[nt][0], acc1[mt][nt], 0, 0, 0);
            acc1[mt][nt] = __builtin_amdgcn_mfma_f32_16x16x32_bf16(a1, bf1[nt][1], acc1[mt][nt], 0, 0, 0);
        }
    }
    short* hid_sh = (short*)(lds_main + HID_OFF);
    #pragma unroll
    for (int mt = 0; mt < 4; mt++)
        #pragma unroll
        for (int nt = 0; nt < 2; nt++) {
            int colg = wbase + nt * 16 + l15;
            #pragma unroll
            for (int rg = 0; rg < 4; rg++) {
                int row = mt * 16 + q * 4 + rg;   // C/D: col=lane&15, row=quad*4+reg
                float v = sspf_fast(acc1[mt][nt][rg] + b1c[nt]);
                hid_sh[row * HID_LD + colg] = (short)f2bf(v);
            }
        }
    __syncthreads();

    // stage 2 MFMA: wv(64x128) = hid(64x128bf16) @ W2(128x128bf16)
    f32x4 acc2[4][2];
    #pragma unroll
    for (int mt = 0; mt < 4; mt++)
        #pragma unroll
        for (int nt = 0; nt < 2; nt++)
            acc2[mt][nt] = (f32x4){0.f, 0.f, 0.f, 0.f};
    #pragma unroll
    for (int mt = 0; mt < 4; mt++) {
        int m = mt * 16 + l15;
        #pragma unroll
        for (int c = 0; c < 4; c++) {
            bf16x8 a = *(const bf16x8*)(hid_sh + m * HID_LD + c * 32 + q * 8);
            #pragma unroll
            for (int nt = 0; nt < 2; nt++)
                acc2[mt][nt] = __builtin_amdgcn_mfma_f32_16x16x32_bf16(a, bf2[nt][c], acc2[mt][nt], 0, 0, 0);
        }
    }
    __syncthreads();

    // epilogue: msg = scale * (wv + b2) * h[src] -> fp32 LDS [64][MSG_LD]
    float* msg_f = (float*)lds_main;
    int head = w >> 1;
    #pragma unroll
    for (int mt = 0; mt < 4; mt++)
        #pragma unroll
        for (int nt = 0; nt < 2; nt++) {
            int colg = wbase + nt * 16 + l15;
            #pragma unroll
            for (int rg = 0; rg < 4; rg++) {
                int row = mt * 16 + q * 4 + rg;
                float sc = scale_s[row][head];
                float hv = h[(size_t)src_s[row] * HD + colg];
                msg_f[row * MSG_LD + colg] = (acc2[mt][nt][rg] + b2c[nt]) * hv * sc;
            }
        }
    __syncthreads();

    // segmented reduction: one write per (dst,col) per tile
    {
        int nseg = nseg_s;
        int col = tid & 127;
        int sp = tid >> 7;
        for (int s = sp; s < nseg; s += 2) {
            int r0 = seg_start_s[s];
            int r1 = (s + 1 < nseg) ? seg_start_s[s + 1] : TILE;
            int d = dst_s[r0];
            if (d < 0) continue;
            float sum = 0.f;
            for (int r = r0; r < r1; r++) sum += msg_f[r * MSG_LD + col];
            float* ap = &agg[(size_t)d * HD + col];
            if (s == 0 || s == nseg - 1) atomicAdd(ap, sum);
            else *ap = sum;
        }
    }
}

// ------------- graph segment-sum with LDS privatization -> d_out directly -------------
__global__ void repr_gsum(const float* __restrict__ hh, const int* __restrict__ gids,
                          float* __restrict__ dout) {
    __shared__ float bins[B_GRAPHS];
    int t = threadIdx.x;
    if (t < B_GRAPHS) bins[t] = 0.f;
    __syncthreads();
    int i = blockIdx.x * 256 + t;
    if (i < N_NODES) atomicAdd(&bins[gids[i]], hh[i]);
    __syncthreads();
    if (t < B_GRAPHS && bins[t] != 0.f) atomicAdd(&dout[t], bins[t]);
}

extern "C" void kernel_launch(void* const* d_in, const int* in_sizes, int n_in,
                              void* d_out, int out_size, void* d_ws, size_t ws_size,
                              hipStream_t stream) {
    (void)in_sizes; (void)n_in; (void)out_size; (void)ws_size;
    const float* R      = (const float*)d_in[0];
    const int*   Z      = (const int*)d_in[1];
    const int*   src    = (const int*)d_in[2];
    const int*   dst    = (const int*)d_in[3];
    const int*   gids   = (const int*)d_in[4];
    const float* emb    = (const float*)d_in[5];
    const float* offs   = (const float*)d_in[6];
    const float* widths = (const float*)d_in[7];
    const float* fc_w   = (const float*)d_in[8];
    const float* attn_l = (const float*)d_in[9];
    const float* attn_r = (const float*)d_in[10];
    const float* fw1    = (const float*)d_in[11];
    const float* fb1    = (const float*)d_in[12];
    const float* fw2    = (const float*)d_in[13];
    const float* fb2    = (const float*)d_in[14];
    const float* mw1    = (const float*)d_in[15];
    const float* mb1    = (const float*)d_in[16];
    const float* mw2    = (const float*)d_in[17];
    const float* mb2    = (const float*)d_in[18];
    const float* ow1    = (const float*)d_in[19];
    const float* ob1    = (const float*)d_in[20];
    const float* ow2    = (const float*)d_in[21];
    const float* ob2    = (const float*)d_in[22];

    char* p = (char*)d_ws;
    float* x      = (float*)p; p += (size_t)N_NODES * 64 * 4;
    float* h      = (float*)p; p += (size_t)N_NODES * 128 * 4;
    float* el     = (float*)p; p += (size_t)N_NODES * 2 * 4;
    float* er     = (float*)p; p += (size_t)N_NODES * 2 * 4;
    float2* md    = (float2*)p; p += (size_t)N_NODES * 8;
    float* agg    = (float*)p; p += (size_t)N_NODES * 128 * 4;
    int*   ssrc_f = (int*)p;   p += (size_t)N_EDGES * 4;
    int*   sdst_f = (int*)p;   p += (size_t)N_EDGES * 4;
    int*   rowptr = (int*)p;   p += (size_t)N_NODES * 4;
    int*   ssrc2  = (int*)p;   p += (size_t)N_EDGES * 4;
    int*   sdst2  = (int*)p;   p += (size_t)N_EDGES * 4;
    float* r2     = (float*)p; p += (size_t)N_EDGES * 4;
    float* r_full = (float*)p; p += (size_t)N_EDGES * 4;
    float* hh     = (float*)p; p += (size_t)N_NODES * 4;
    short* w1t    = (short*)p; p += (size_t)L_LAYERS * 8192 * 2;
    short* w2t    = (short*)p; p += (size_t)L_LAYERS * 16384 * 2;
    int*   bsumA  = (int*)p;   p += 1024;
    int*   bprefA = (int*)p;   p += 1024;
    int*   bsumB  = (int*)p;   p += 1024;
    int*   bprefB = (int*)p;   p += 1024;
    int*   ecF    = (int*)p;   p += 256;
    int*   ecS    = (int*)p;   p += 256;
    // scan temporaries aliased into x (x written by repr_embed_h, strictly after
    // repr_scatter in stream order):
    int* count_f = (int*)x;
    int* excl_f  = (int*)((char*)x + 256 * 1024);
    int* cur_f   = (int*)((char*)x + 512 * 1024);
    int* count_s = (int*)((char*)x + 768 * 1024);
    int* excl_s  = (int*)((char*)x + 1024 * 1024);
    int* cur_s   = (int*)((char*)x + 1280 * 1024);

    // one-time prep: weight transpose + zero counters + zero d_out
    repr_prep<<<(PREP_W + 2 * N_NODES + B_GRAPHS + 255) / 256, 256, 0, stream>>>(
        fw1, fw2, w1t, w2t, count_f, count_s, (float*)d_out);
    repr_hist<<<N_EDGES / 256, 256, 0, stream>>>(R, src, dst, count_f, count_s, r_full);
    repr_scanA2<<<2 * NCHUNK, 256, 0, stream>>>(count_f, excl_f, bsumA,
                                                count_s, excl_s, bsumB);
    repr_scanB2<<<2, 256, 0, stream>>>(bsumA, bprefA, ecF, bsumB, bprefB, ecS);
    repr_scanC2<<<2 * NCHUNK, 256, 0, stream>>>(excl_f, bprefA, cur_f, rowptr,
                                                excl_s, bprefB, cur_s);
    repr_scatter<<<N_EDGES / 256, 256, 0, stream>>>(
        r_full, src, dst, cur_f, cur_s, ssrc_f, sdst_f, ssrc2, sdst2, r2);

    repr_embed_h<<<NBLK, 256, 0, stream>>>(
        emb, Z, fc_w, attn_l, attn_r, x, h, el, er);

    for (int l = 0; l < L_LAYERS; l++) {
        repr_alpha<<<(N_NODES * 16 + 255) / 256, 256, 0, stream>>>(
            ssrc_f, rowptr, el, er, md, agg);
        repr_msg<<<N_EDGES / TILE, 256, 0, stream>>>(
            ssrc2, sdst2, r2, ecS, el, er, md, h, offs, widths,
            w1t + (size_t)l * 8192, fb1 + (size_t)l * HID_DIM,
            w2t + (size_t)l * 16384, fb2 + (size_t)l * HD, agg);
        if (l < L_LAYERS - 1) {
            repr_mlp_h<<<NBLK, 256, 0, stream>>>(
                agg, mw1 + (size_t)l * 128 * 64, mb1 + l * 64,
                mw2 + (size_t)l * 64 * 64, mb2 + l * 64,
                fc_w + (size_t)(l + 1) * 64 * 128, attn_l + (l + 1) * 128,
                attn_r + (l + 1) * 128, x, h, el, er);
        } else {
            repr_mlp_out<<<NBLK, 256, 0, stream>>>(
                agg, mw1 + (size_t)l * 128 * 64, mb1 + l * 64,
                mw2 + (size_t)l * 64 * 64, mb2 + l * 64,
                ow1, ob1, ow2, ob2, x, hh);
        }
    }
    repr_gsum<<<NCHUNK, 256, 0, stream>>>(hh, gids, (float*)d_out);
}